// Round 20
// baseline (163.883 us; speedup 1.0000x reference)
//
#include <hip/hip_runtime.h>
#include <hip/hip_bf16.h>
#include <stdint.h>

// B=4, T=2048, D_MODEL=1024, H=16, hd=64
// Q/K token-major: [B*T, 1024], head h at cols h*64..h*64+63.
// V is stored TRANSPOSED: Vt[bh][d][t] = Vt[bh*131072 + d*2048 + t] (bf16).
// W_Q is pre-scaled by 0.125*log2(e) so softmax runs in log2 domain.
// wqkv = [3072 rows][1024] (wq rows 0-1023, wk 1024-2047, wv 2048-3071).

typedef __attribute__((ext_vector_type(8))) short short8;    // 8 x bf16 (4 VGPRs)
typedef __attribute__((ext_vector_type(4))) short short4v;
typedef __attribute__((ext_vector_type(4))) float floatx4;

#define LOG2E 1.4426950408889634f

__device__ __forceinline__ void gload_lds16(const void* g, void* l) {
  __builtin_amdgcn_global_load_lds(
      (const __attribute__((address_space(1))) void*)g,
      (__attribute__((address_space(3))) void*)l, 16, 0, 0);
}

__device__ __forceinline__ short f2bf(float f) {
  __hip_bfloat16 h = __float2bfloat16(f);
  return *reinterpret_cast<short*>(&h);
}

// ---------------- fp32 -> bf16 conversion ----------------
__global__ __launch_bounds__(256) void cvt_f32_bf16(const float* __restrict__ src,
                                                    short* __restrict__ dst, int n4,
                                                    float scale) {
  const int i = blockIdx.x * blockDim.x + threadIdx.x;
  if (i >= n4) return;
  const float4 v = reinterpret_cast<const float4*>(src)[i];
  short4v o;
  o.x = f2bf(v.x * scale); o.y = f2bf(v.y * scale);
  o.z = f2bf(v.z * scale); o.w = f2bf(v.w * scale);
  reinterpret_cast<short4v*>(dst)[i] = o;
}

__global__ __launch_bounds__(256) void cvt_weights(const float* __restrict__ wq,
                                                   const float* __restrict__ wk,
                                                   const float* __restrict__ wv,
                                                   const float* __restrict__ wo,
                                                   short* __restrict__ dst0,
                                                   float qscale) {
  const int y = blockIdx.y;
  const float* src = (y == 0) ? wq : (y == 1) ? wk : (y == 2) ? wv : wo;
  const float scale = (y == 0) ? qscale : 1.0f;
  short* dst = dst0 + (size_t)y * 1048576;
  const int i = blockIdx.x * blockDim.x + threadIdx.x;
  const float4 v = reinterpret_cast<const float4*>(src)[i];
  short4v o;
  o.x = f2bf(v.x * scale); o.y = f2bf(v.y * scale);
  o.z = f2bf(v.z * scale); o.w = f2bf(v.w * scale);
  reinterpret_cast<short4v*>(&dst[i * 4])[0] = o;
}

// ---- QKV as one C[8192,3072] GEMM: m201-style 8-phase 256x256, BK=64 ----
// 512 thr = 8 waves (2M x 4N); per-wave 128x64 out (acc[8][4]).
// LDS: 2 x (A 256x64 + B 256x64) bf16 = 128 KB. Swizzle: chunk c of row r at
// slot c^(r&7) (verified 0-conflict this session). Per iteration (2 K-tiles,
// 8 phases): quadrant MFMA (16/phase), one half-tile DMA (2 gloads) per phase:
// ph1/2: A(t+1)->buf1, ph3/4: B(t+2)->buf0, ph5/6: A(t+2)->buf0,
// ph7/8: B(t+3)->buf1. Region-free: B-halves free after ph2 (all B reads in
// ph1+ph2), A-halves after ph4 (aL ph1/2, aH ph3/4), mirrored for buf1.
// vmcnt(4) at ph4/ph8 only: drains exactly the next tile's 8 loads (in-order),
// leaves this half-iter's 4 in flight. z = n0>>10 constant per block.
__global__ __launch_bounds__(512) void gemm_qkv(
    const short* __restrict__ xb, const short* __restrict__ wqkv,
    short* __restrict__ Qb, short* __restrict__ Kb, short* __restrict__ Vt) {
  __shared__ short lA[2][256 * 64];   // 64 KB
  __shared__ short lB[2][256 * 64];   // 64 KB
  const int tid = threadIdx.x;
  const int lane = tid & 63;
  const int w = tid >> 6;             // 0..7
  const int wm = w >> 2, wn = w & 3;  // 2M x 4N
  const int lrow = lane & 15, lgrp = lane >> 4;

  const int flat = blockIdx.x;        // 0..383
  const int xcd = flat & 7, j = flat >> 3;       // j 0..47
  const int m0 = (xcd * 4 + j / 12) * 256;
  const int n0 = (j % 12) * 256;

  floatx4 acc[8][4] = {};

  const int srow = tid >> 3;          // 0..63
  const int scb = (tid & 7) ^ (srow & 7);
  const short* ag = xb + (size_t)(m0 + srow) * 1024 + scb * 8;
  const short* bg = wqkv + (size_t)(n0 + srow) * 1024 + scb * 8;

  // stage half h (128 rows) of K-tile kt into buffer buf: 2 gloads
  auto stA = [&](int buf, int h, int kt) {
    const short* s = ag + (size_t)kt * 64 + (size_t)h * 131072;
    gload_lds16(s, &lA[buf][(h * 1024 + tid) * 8]);
    gload_lds16(s + 65536, &lA[buf][(h * 1024 + 512 + tid) * 8]);
  };
  auto stB = [&](int buf, int h, int kt) {
    const short* s = bg + (size_t)kt * 64 + (size_t)h * 131072;
    gload_lds16(s, &lB[buf][(h * 1024 + tid) * 8]);
    gload_lds16(s + 65536, &lB[buf][(h * 1024 + 512 + tid) * 8]);
  };

  // fragment reads (row&7 == lrow&7: wm*128, wn*64, *16 are 0 mod 8)
  auto rdA = [&](int buf, int mf, int ks) {
    const int row = wm * 128 + mf * 16 + lrow;
    return *reinterpret_cast<const short8*>(
        &lA[buf][row * 64 + (((ks * 4 + lgrp) ^ (lrow & 7)) * 8)]);
  };
  auto rdB = [&](int buf, int nf, int ks) {
    const int row = wn * 64 + nf * 16 + lrow;
    return *reinterpret_cast<const short8*>(
        &lB[buf][row * 64 + (((ks * 4 + lgrp) ^ (lrow & 7)) * 8)]);
  };

#define MIDBAR_LGKM                                            \
  __builtin_amdgcn_sched_barrier(0);                           \
  __builtin_amdgcn_s_barrier();                                \
  asm volatile("s_waitcnt lgkmcnt(0)" ::: "memory");           \
  __builtin_amdgcn_sched_barrier(0);
#define MIDBAR_PLAIN                                           \
  __builtin_amdgcn_sched_barrier(0);                           \
  __builtin_amdgcn_s_barrier();                                \
  __builtin_amdgcn_sched_barrier(0);
#define ENDBAR                                                 \
  __builtin_amdgcn_sched_barrier(0);                           \
  __builtin_amdgcn_s_barrier();                                \
  __builtin_amdgcn_sched_barrier(0);

  // one K-tile = 4 phases. pfAo: stage A(kt+1)->other buf (ph1,ph2).
  // pfBs: stage B(kt+2)->this buf (ph3,ph4). vmend: vmcnt at ph4 end (-1 none).
  auto tile4 = [&](int cbuf, int kt, bool pfAo, bool pfBs, int vmend) {
    const int obuf = cbuf ^ 1;
    short8 aL[2][4], aH[2][4], b[2][4];
    // ---- ph1: reads aL + b01; stage A-half0(kt+1)
#pragma unroll
    for (int ks = 0; ks < 2; ++ks) {
#pragma unroll
      for (int mf = 0; mf < 4; ++mf) aL[ks][mf] = rdA(cbuf, mf, ks);
      b[ks][0] = rdB(cbuf, 0, ks);
      b[ks][1] = rdB(cbuf, 1, ks);
    }
    if (pfAo) stA(obuf, 0, kt + 1);
    MIDBAR_LGKM;
    __builtin_amdgcn_s_setprio(1);
#pragma unroll
    for (int ks = 0; ks < 2; ++ks)
#pragma unroll
      for (int mf = 0; mf < 4; ++mf)
#pragma unroll
        for (int nf = 0; nf < 2; ++nf)
          acc[mf][nf] = __builtin_amdgcn_mfma_f32_16x16x32_bf16(aL[ks][mf], b[ks][nf], acc[mf][nf], 0, 0, 0);
    __builtin_amdgcn_s_setprio(0);
    ENDBAR;
    // ---- ph2: reads b23; stage A-half1(kt+1)
#pragma unroll
    for (int ks = 0; ks < 2; ++ks) {
      b[ks][2] = rdB(cbuf, 2, ks);
      b[ks][3] = rdB(cbuf, 3, ks);
    }
    if (pfAo) stA(obuf, 1, kt + 1);
    MIDBAR_LGKM;
    __builtin_amdgcn_s_setprio(1);
#pragma unroll
    for (int ks = 0; ks < 2; ++ks)
#pragma unroll
      for (int mf = 0; mf < 4; ++mf)
#pragma unroll
        for (int nf = 2; nf < 4; ++nf)
          acc[mf][nf] = __builtin_amdgcn_mfma_f32_16x16x32_bf16(aL[ks][mf], b[ks][nf], acc[mf][nf], 0, 0, 0);
    __builtin_amdgcn_s_setprio(0);
    ENDBAR;
    // ---- ph3: reads aH; stage B-half0(kt+2)
#pragma unroll
    for (int ks = 0; ks < 2; ++ks)
#pragma unroll
      for (int mf = 0; mf < 4; ++mf) aH[ks][mf] = rdA(cbuf, 4 + mf, ks);
    if (pfBs) stB(cbuf, 0, kt + 2);
    MIDBAR_LGKM;
    __builtin_amdgcn_s_setprio(1);
#pragma unroll
    for (int ks = 0; ks < 2; ++ks)
#pragma unroll
      for (int mf = 0; mf < 4; ++mf)
#pragma unroll
        for (int nf = 0; nf < 2; ++nf)
          acc[4 + mf][nf] = __builtin_amdgcn_mfma_f32_16x16x32_bf16(aH[ks][mf], b[ks][nf], acc[4 + mf][nf], 0, 0, 0);
    __builtin_amdgcn_s_setprio(0);
    ENDBAR;
    // ---- ph4: no reads; stage B-half1(kt+2); vmcnt at end
    if (pfBs) stB(cbuf, 1, kt + 2);
    MIDBAR_PLAIN;
    __builtin_amdgcn_s_setprio(1);
#pragma unroll
    for (int ks = 0; ks < 2; ++ks)
#pragma unroll
      for (int mf = 0; mf < 4; ++mf)
#pragma unroll
        for (int nf = 2; nf < 4; ++nf)
          acc[4 + mf][nf] = __builtin_amdgcn_mfma_f32_16x16x32_bf16(aH[ks][mf], b[ks][nf], acc[4 + mf][nf], 0, 0, 0);
    __builtin_amdgcn_s_setprio(0);
    __builtin_amdgcn_sched_barrier(0);
    if (vmend == 4) asm volatile("s_waitcnt vmcnt(4)" ::: "memory");
    else if (vmend == 0) asm volatile("s_waitcnt vmcnt(0)" ::: "memory");
    __builtin_amdgcn_s_barrier();
    __builtin_amdgcn_sched_barrier(0);
  };

  // prologue: tile0 (8 loads) then B(1) (4 loads); drain tile0, keep B(1)
  stA(0, 0, 0); stA(0, 1, 0);
  stB(0, 0, 0); stB(0, 1, 0);
  stB(1, 0, 1); stB(1, 1, 1);
  asm volatile("s_waitcnt vmcnt(4)" ::: "memory");
  __builtin_amdgcn_s_barrier();
  __builtin_amdgcn_sched_barrier(0);

#pragma unroll 1
  for (int i = 0; i < 7; ++i) {
    const int t = 2 * i;
    tile4(0, t, true, true, 4);
    tile4(1, t + 1, true, true, 4);
  }
  tile4(0, 14, true, false, 0);     // stages A(15); waits everything for tile15
  tile4(1, 15, false, false, -1);   // final tile, no stage, no wait

  // epilogue: z constant per block (n0 multiple of 256; 1024 % 256 == 0)
  const int z = n0 >> 10;
  const int colbase = (n0 & 1023) + wn * 64;
  if (z == 2) {
#pragma unroll
    for (int mf = 0; mf < 8; ++mf) {
#pragma unroll
      for (int nf = 0; nf < 4; ++nf) {
        short4v pk;
#pragma unroll
        for (int r = 0; r < 4; ++r) pk[r] = f2bf(acc[mf][nf][r]);
        const int t0 = m0 + wm * 128 + mf * 16 + lgrp * 4;  // 4 consecutive tokens
        const int ch = colbase + nf * 16 + lrow;            // channel 0..1023
        const int bh = ((t0 >> 11) << 4) + (ch >> 6);
        *reinterpret_cast<short4v*>(
            &Vt[(size_t)bh * 131072 + (size_t)(ch & 63) * 2048 + (t0 & 2047)]) = pk;
      }
    }
  } else {
    short* C = (z == 0) ? Qb : Kb;
#pragma unroll
    for (int mf = 0; mf < 8; ++mf) {
#pragma unroll
      for (int nf = 0; nf < 4; ++nf) {
#pragma unroll
        for (int r = 0; r < 4; ++r) {
          const int grow = m0 + wm * 128 + mf * 16 + lgrp * 4 + r;
          const int gcol = colbase + nf * 16 + lrow;
          C[(size_t)grow * 1024 + gcol] = f2bf(acc[mf][nf][r]);
        }
      }
    }
  }
#undef MIDBAR_LGKM
#undef MIDBAR_PLAIN
#undef ENDBAR
}

// ---- single-output GEMM (O-projection), r14 structure (unchanged, passing) ----
template <int MODE>
__device__ __forceinline__ void gemm256_body(const short* __restrict__ A,
                                             const short* __restrict__ B,
                                             void* __restrict__ Cout,
                                             int m0, int n0,
                                             short* __restrict__ la0,
                                             short* __restrict__ la1,
                                             short* __restrict__ la2,
                                             short* __restrict__ lb0,
                                             short* __restrict__ lb1,
                                             short* __restrict__ lb2) {
  const int tid = threadIdx.x;
  const int lane = tid & 63;
  const int w = tid >> 6;
  const int wm = w >> 1, wn = w & 1;
  const int lrow = lane & 15, lgrp = lane >> 4;

  floatx4 acc[4][4] = {};

  const int srow = tid >> 2;
  const int scb = (tid & 3) ^ (srow & 3) ^ ((srow & 4) >> 1);
  const short* ag = A + (size_t)(m0 + srow) * 1024 + scb * 8;
  const short* bg = B + (size_t)(n0 + srow) * 1024 + scb * 8;

  auto stage3 = [&](short* la, short* lb) {
    gload_lds16(ag, la + tid * 8);
    gload_lds16(ag + 128 * 1024, la + (512 + tid) * 8);
    gload_lds16(bg, lb + tid * 8);
    ag += 32; bg += 32;
  };

  const int slA = (lgrp ^ (lrow & 3) ^ ((lrow & 4) >> 1)) * 8;

  auto tile = [&](const short* la, const short* lb, short* na, short* nb, bool pf) {
    if (pf) stage3(na, nb);
    short8 af[4], bf[4];
#pragma unroll
    for (int mf = 0; mf < 4; ++mf) {
      const int row = wm * 64 + mf * 16 + lrow;
      af[mf] = *reinterpret_cast<const short8*>(&la[row * 32 + slA]);
    }
#pragma unroll
    for (int nf = 0; nf < 4; ++nf) {
      const int row = wn * 64 + nf * 16 + lrow;
      bf[nf] = *reinterpret_cast<const short8*>(&lb[row * 32 + slA]);
    }
    __builtin_amdgcn_s_setprio(1);
#pragma unroll
    for (int mf = 0; mf < 4; ++mf)
#pragma unroll
      for (int nf = 0; nf < 4; ++nf)
        acc[mf][nf] = __builtin_amdgcn_mfma_f32_16x16x32_bf16(af[mf], bf[nf], acc[mf][nf], 0, 0, 0);
    __builtin_amdgcn_s_setprio(0);
  };

  auto tiletop = [&](int n) {
    __builtin_amdgcn_sched_barrier(0);
    if (n == 0)
      asm volatile("s_waitcnt vmcnt(0)" ::: "memory");
    else
      asm volatile("s_waitcnt vmcnt(3)" ::: "memory");
    __builtin_amdgcn_s_barrier();
    __builtin_amdgcn_sched_barrier(0);
  };

  stage3(la0, lb0);
  stage3(la1, lb1);

#pragma unroll 1
  for (int kt = 0; kt < 30; kt += 3) {
    tiletop(3); tile(la0, lb0, la2, lb2, true);
    tiletop(3); tile(la1, lb1, la0, lb0, true);
    tiletop(3); tile(la2, lb2, la1, lb1, true);
  }
  tiletop(3); tile(la0, lb0, nullptr, nullptr, false);
  tiletop(0); tile(la1, lb1, nullptr, nullptr, false);

#pragma unroll
  for (int mf = 0; mf < 4; ++mf) {
#pragma unroll
    for (int nf = 0; nf < 4; ++nf) {
#pragma unroll
      for (int r = 0; r < 4; ++r) {
        const int grow = m0 + wm * 64 + mf * 16 + lgrp * 4 + r;
        const int gcol = n0 + wn * 64 + nf * 16 + lrow;
        if (MODE == 1)
          reinterpret_cast<short*>(Cout)[(size_t)grow * 1024 + gcol] = f2bf(acc[mf][nf][r]);
        else
          reinterpret_cast<float*>(Cout)[(size_t)grow * 1024 + gcol] = acc[mf][nf][r];
      }
    }
  }
}

__global__ __launch_bounds__(512) void gemm_out(const short* __restrict__ Ob,
                                                const short* __restrict__ wo,
                                                float* __restrict__ out) {
  __shared__ short lds_a[3][256 * 32];
  __shared__ short lds_b[3][128 * 32];
  const int flat = blockIdx.x;
  const int xcd = flat & 7, rest = flat >> 3;
  const int nblk = rest & 7, pg = rest >> 3;
  const int panel = pg * 8 + xcd;
  gemm256_body<0>(Ob, wo, out, panel * 256, nblk * 128,
                  lds_a[0], lds_a[1], lds_a[2], lds_b[0], lds_b[1], lds_b[2]);
}

// ---------------- flash attention (unchanged from round 19 — passing) ----------------
__global__ __launch_bounds__(256, 4) void attn_fwd(const short* __restrict__ Q,
                                                   const short* __restrict__ K,
                                                   const short* __restrict__ Vt,
                                                   short* __restrict__ O) {
  __shared__ short lds_k[2][64 * 64];    // 16 KB
  __shared__ short lds_v[2][64 * 64];    // 16 KB : [d][k] swizzled
  __shared__ short lds_p[4][16 * 64];    //  8 KB : [wave][16q][64k] swizzled (reused per qt)

  const int tid = threadIdx.x;
  const int lane = tid & 63;
  const int w = tid >> 6;                // 0..3
  const int lrow = lane & 15, lgrp = lane >> 4;
  const int flat = blockIdx.x;
  const int bh = flat & 63;              // XCD-locality: same bh -> same XCD
  const int p = flat >> 6;               // 0..15
  const int qc = 4 * (((p & 3) + (p >> 2)) & 3) + (p >> 2);  // Latin-square chunk
  const int b = bh >> 4, h = bh & 15;

  const size_t base = (size_t)b * 2048 * 1024 + h * 64;
  const size_t vbase = (size_t)bh * 131072;

  const int srow = tid >> 3;                         // 0..31
  const int scb = (tid & 7) ^ (srow & 7);
  const size_t koff = (size_t)srow * 1024 + scb * 8;
  const size_t voff = (size_t)srow * 2048 + scb * 8;
  short* const kd0 = &lds_k[0][tid * 8];
  short* const kd1 = &lds_k[1][tid * 8];
  short* const vd0 = &lds_v[0][tid * 8];
  short* const vd1 = &lds_v[1][tid * 8];

  auto stageK = [&](short* ldst, const short* gsrc) {
    gload_lds16(gsrc, ldst);
    gload_lds16(gsrc + 32 * 1024, ldst + 2048);
  };
  auto stageV = [&](short* ldst, const short* gsrc) {
    gload_lds16(gsrc, ldst);
    gload_lds16(gsrc + 32 * 2048, ldst + 2048);
  };

  const int qw = qc * 128 + w * 32;          // wave's first q row
  const int lastkb = 2 * qc + (w >> 1);      // wave's diag KV tile
  const int nkb = 2 * qc + 2;                // block KV-tile count

  short8 qf[2][2];
#pragma unroll
  for (int qt = 0; qt < 2; ++qt) {
    const short* qp = Q + base + (size_t)(qw + qt * 16 + lrow) * 1024 + lgrp * 8;
    qf[qt][0] = *reinterpret_cast<const short8*>(qp);
    qf[qt][1] = *reinterpret_cast<const short8*>(qp + 32);
  }

  floatx4 oacc[2][4] = {};
  float lsum0 = 0.f, lsum1 = 0.f;

  const short* kg = K + base + koff;
  const short* vg = Vt + vbase + voff;

  auto body = [&](int kb, const short* __restrict__ ldsk,
                  const short* __restrict__ ldsv) {
    if (kb > lastkb) return;
    floatx4 s[2][4];
    __builtin_amdgcn_s_setprio(1);
#pragma unroll
    for (int nf = 0; nf < 4; ++nf) {
      const short8 kf0 = *reinterpret_cast<const short8*>(
          &ldsk[(nf * 16 + lrow) * 64 + ((lgrp) ^ (lrow & 7)) * 8]);
      const short8 kf1 = *reinterpret_cast<const short8*>(
          &ldsk[(nf * 16 + lrow) * 64 + ((4 + lgrp) ^ (lrow & 7)) * 8]);
#pragma unroll
      for (int qt = 0; qt < 2; ++qt) {
        floatx4 z = {};
        z = __builtin_amdgcn_mfma_f32_16x16x32_bf16(kf0, qf[qt][0], z, 0, 0, 0);
        z = __builtin_amdgcn_mfma_f32_16x16x32_bf16(kf1, qf[qt][1], z, 0, 0, 0);
        s[qt][nf] = z;
      }
    }
    __builtin_amdgcn_s_setprio(0);

    if (kb == lastkb) {
#pragma unroll
      for (int qt = 0; qt < 2; ++qt)
#pragma unroll
        for (int nf = 0; nf < 4; ++nf)
#pragma unroll
          for (int r = 0; r < 4; ++r) {
            const int kg_ = kb * 64 + nf * 16 + lgrp * 4 + r;
            const int qg_ = qw + qt * 16 + lrow;
            if (kg_ > qg_) s[qt][nf][r] = -1e30f;
          }
    }

    short8 pa[2][2];
#pragma unroll
    for (int qt = 0; qt < 2; ++qt) {
      float ls = 0.f;
#pragma unroll
      for (int nf = 0; nf < 4; ++nf) {
        const float p0 = __builtin_amdgcn_exp2f(s[qt][nf][0]);
        const float p1 = __builtin_amdgcn_exp2f(s[qt][nf][1]);
        const float p2 = __builtin_amdgcn_exp2f(s[qt][nf][2]);
        const float p3 = __builtin_amdgcn_exp2f(s[qt][nf][3]);
        ls += (p0 + p1) + (p2 + p3);
        short4v pk;
        pk.x = f2bf(p0); pk.y = f2bf(p1); pk.z = f2bf(p2); pk.w = f2bf(p3);
        const int c8 = (nf * 4 + lgrp) ^ ((lrow & 7) << 1);
        *reinterpret_cast<short4v*>(&lds_p[w][lrow * 64 + c8 * 4]) = pk;
      }
      if (qt == 0) lsum0 += ls; else lsum1 += ls;
      const int c0 = ((lgrp) ^ (lrow & 7)) * 8;
      const int c1 = ((4 + lgrp) ^ (lrow & 7)) * 8;
      pa[qt][0] = *reinterpret_cast<const short8*>(&lds_p[w][lrow * 64 + c0]);
      pa[qt][1] = *reinterpret_cast<const short8*>(&lds_p[w][lrow * 64 + c1]);
    }

    __builtin_amdgcn_s_setprio(1);
#pragma unroll
    for (int nf = 0; nf < 4; ++nf) {
      const short8 vf0 = *reinterpret_cast<const short8*>(
          &ldsv[(nf * 16 + lrow) * 64 + ((lgrp) ^ (lrow & 7)) * 8]);
      const short8 vf1 = *reinterpret_cast<const short8*>(
          &ldsv[(nf * 16 + lrow) * 64 + ((4 + lgrp) ^ (lrow & 7)) * 8]);
#pragma unroll
      for (int qt = 0; qt < 2; ++qt) {
        oacc[qt][nf] = __builtin_amdgcn_mfma_f32_16x16x32_bf16(pa[qt][0], vf0, oacc[qt][nf], 0, 0, 0);
        oacc[qt][nf] = __builtin_amdgcn_mfma_f32_16x16x32_bf16(pa[qt][1], vf1, oacc[qt][nf], 0, 0, 0);
      }
    }
    __builtin_amdgcn_s_setprio(0);
  };

  stageK(kd0, kg); kg += 65536;
  stageV(vd0, vg); vg += 64;
  __syncthreads();

#pragma unroll 1
  for (int kb = 0; kb < nkb; kb += 2) {
    if (kb + 1 < nkb) { stageK(kd1, kg); kg += 65536; stageV(vd1, vg); vg += 64; }
    body(kb, lds_k[0], lds_v[0]);
    __syncthreads();
    if (kb + 1 >= nkb) break;
    if (kb + 2 < nkb) { stageK(kd0, kg); kg += 65536; stageV(vd0, vg); vg += 64; }
    body(kb + 1, lds_k[1], lds_v[1]);
    __syncthreads();
  }

  lsum0 += __shfl_xor(lsum0, 16, 64);
  lsum0 += __shfl_xor(lsum0, 32, 64);
  lsum1 += __shfl_xor(lsum1, 16, 64);
  lsum1 += __shfl_xor(lsum1, 32, 64);
#pragma unroll
  for (int qt = 0; qt < 2; ++qt) {
    const float lw = qt == 0 ? lsum0 : lsum1;
#pragma unroll
    for (int r = 0; r < 4; ++r) {
      const float linv = 1.0f / __shfl(lw, lgrp * 4 + r, 64);
      const int t = qw + qt * 16 + lgrp * 4 + r;
#pragma unroll
      for (int nf = 0; nf < 4; ++nf)
        O[base + (size_t)t * 1024 + nf * 16 + lrow] = f2bf(oacc[qt][nf][r] * linv);
    }
  }
}

// ---------------- launcher ----------------
extern "C" void kernel_launch(void* const* d_in, const int* in_sizes, int n_in,
                              void* d_out, int out_size, void* d_ws, size_t ws_size,
                              hipStream_t stream) {
  const float* x  = (const float*)d_in[0];
  const float* Wq = (const float*)d_in[1];
  const float* Wk = (const float*)d_in[2];
  const float* Wv = (const float*)d_in[3];
  const float* Wo = (const float*)d_in[4];

  uint8_t* ws = (uint8_t*)d_ws;
  short* xb  = (short*)(ws + 0);           // 8192x1024 bf16  (16 MiB)
  short* wqb = (short*)(ws + 16777216);    // 4 x 1024x1024 bf16, contiguous (wqkv = first 3)
  short* wob = (short*)(ws + 23068672);
  short* Qb  = (short*)(ws + 25165824);    // 8192x1024 bf16
  short* Kb  = (short*)(ws + 41943040);
  short* Vt  = (short*)(ws + 58720256);    // [64 bh][64 d][2048 t] bf16
  short* Ob  = (short*)(ws + 75497472);
  if (ws_size < 92274688ull) return;  // fail loudly (output stays poisoned)

  const float qscale = 0.125f * LOG2E;     // fold head-scale + log2e into W_Q

  cvt_f32_bf16<<<8192, 256, 0, stream>>>(x, xb, 2097152, 1.0f);
  cvt_weights<<<dim3(1024, 4), 256, 0, stream>>>(Wq, Wk, Wv, Wo, wqb, qscale);

  gemm_qkv<<<384, 512, 0, stream>>>(xb, wqb, Qb, Kb, Vt);
  attn_fwd<<<1024, 256, 0, stream>>>(Qb, Kb, Vt, Ob);
  gemm_out<<<256, 512, 0, stream>>>(Ob, wob, (float*)d_out);
}

// Round 21
// 146.373 us; speedup vs baseline: 1.1196x; 1.1196x over previous
//
#include <hip/hip_runtime.h>
#include <hip/hip_bf16.h>
#include <stdint.h>

// B=4, T=2048, D_MODEL=1024, H=16, hd=64
// Q/K token-major: [B*T, 1024], head h at cols h*64..h*64+63.
// V is stored TRANSPOSED: Vt[bh][d][t] = Vt[bh*131072 + d*2048 + t] (bf16).
// W_Q is pre-scaled by 0.125*log2(e) so softmax runs in log2 domain.

typedef __attribute__((ext_vector_type(8))) short short8;    // 8 x bf16 (4 VGPRs)
typedef __attribute__((ext_vector_type(4))) short short4v;
typedef __attribute__((ext_vector_type(4))) float floatx4;

#define LOG2E 1.4426950408889634f

__device__ __forceinline__ void gload_lds16(const void* g, void* l) {
  __builtin_amdgcn_global_load_lds(
      (const __attribute__((address_space(1))) void*)g,
      (__attribute__((address_space(3))) void*)l, 16, 0, 0);
}

__device__ __forceinline__ short f2bf(float f) {
  __hip_bfloat16 h = __float2bfloat16(f);
  return *reinterpret_cast<short*>(&h);
}

// ---------------- fused fp32 -> bf16 conversion (x + all 4 weights) ----------------
// i < 2097152 : x (scale 1). Else weight y = (i-2097152)>>18 (wq scaled by qscale).
__global__ __launch_bounds__(256) void cvt_all(const float* __restrict__ x,
                                               const float* __restrict__ wq,
                                               const float* __restrict__ wk,
                                               const float* __restrict__ wv,
                                               const float* __restrict__ wo,
                                               short* __restrict__ xb,
                                               short* __restrict__ wb0,
                                               float qscale) {
  const int i = blockIdx.x * 256 + threadIdx.x;   // 0..3145727 float4-groups
  const float* src;
  short* dst;
  float scale = 1.0f;
  int idx;
  if (i < 2097152) {
    src = x; dst = xb; idx = i;
  } else {
    const int j = i - 2097152;      // 0..1048575
    const int y = j >> 18;          // 0..3
    idx = j & 262143;
    src = (y == 0) ? wq : (y == 1) ? wk : (y == 2) ? wv : wo;
    if (y == 0) scale = qscale;
    dst = wb0 + (size_t)y * 1048576;
  }
  const float4 v = reinterpret_cast<const float4*>(src)[idx];
  short4v o;
  o.x = f2bf(v.x * scale); o.y = f2bf(v.y * scale);
  o.z = f2bf(v.z * scale); o.w = f2bf(v.w * scale);
  reinterpret_cast<short4v*>(dst)[idx] = o;
}

// ---- MERGED QKV GEMM (round 16 body — measured 59.7us, passing) ----
__global__ __launch_bounds__(512) void gemm_qkv(
    const short* __restrict__ xb, const short* __restrict__ wqkv,
    short* __restrict__ Qb, short* __restrict__ Kb, short* __restrict__ Vt) {
  __shared__ short lds_a[3][256 * 32];      // 48 KB
  __shared__ short lds_b[3][3 * 128 * 32];  // 72 KB : [buf][z][128r][32k]
  const int tid = threadIdx.x;
  const int lane = tid & 63;
  const int w = tid >> 6;                 // 0..7
  const int wm = w >> 1, wn = w & 1;      // 4M x 2N wave grid
  const int lrow = lane & 15, lgrp = lane >> 4;

  const int flat = blockIdx.x;            // 0..255
  const int n0 = (flat & 7) * 128;        // XCD-resident weight panel
  const int m0 = (flat >> 3) * 256;

  floatx4 acc[3][4][4] = {};

  const int srow = tid >> 2;              // 0..127
  const int scb = (tid & 3) ^ (srow & 3) ^ ((srow & 4) >> 1);
  const short* ag = xb + (size_t)(m0 + srow) * 1024 + scb * 8;
  const short* bg = wqkv + (size_t)(n0 + srow) * 1024 + scb * 8;

  auto stage5 = [&](short* la, short* lb) {
    gload_lds16(ag, la + tid * 8);
    gload_lds16(ag + 128 * 1024, la + (512 + tid) * 8);
    gload_lds16(bg,           lb + tid * 8);
    gload_lds16(bg + 1048576, lb + 4096 + tid * 8);
    gload_lds16(bg + 2097152, lb + 8192 + tid * 8);
    ag += 32; bg += 32;
  };

  const int slA = (lgrp ^ (lrow & 3) ^ ((lrow & 4) >> 1)) * 8;

  auto tile = [&](const short* la, const short* lb, short* na, short* nb, bool pf) {
    if (pf) stage5(na, nb);
    short8 af[4];
#pragma unroll
    for (int mf = 0; mf < 4; ++mf)
      af[mf] = *reinterpret_cast<const short8*>(
          &la[(wm * 64 + mf * 16 + lrow) * 32 + slA]);
#pragma unroll
    for (int z = 0; z < 3; ++z) {
      short8 bf[4];
#pragma unroll
      for (int nf = 0; nf < 4; ++nf)
        bf[nf] = *reinterpret_cast<const short8*>(
            &lb[z * 4096 + (wn * 64 + nf * 16 + lrow) * 32 + slA]);
      __builtin_amdgcn_s_setprio(1);
#pragma unroll
      for (int mf = 0; mf < 4; ++mf)
#pragma unroll
        for (int nf = 0; nf < 4; ++nf)
          acc[z][mf][nf] = __builtin_amdgcn_mfma_f32_16x16x32_bf16(
              af[mf], bf[nf], acc[z][mf][nf], 0, 0, 0);
      __builtin_amdgcn_s_setprio(0);
    }
  };

  auto tiletop = [&](int n) {
    __builtin_amdgcn_sched_barrier(0);
    if (n == 0)
      asm volatile("s_waitcnt vmcnt(0)" ::: "memory");
    else
      asm volatile("s_waitcnt vmcnt(5)" ::: "memory");
    __builtin_amdgcn_s_barrier();
    __builtin_amdgcn_sched_barrier(0);
  };

  stage5(lds_a[0], lds_b[0]);
  stage5(lds_a[1], lds_b[1]);

#pragma unroll 1
  for (int kt = 0; kt < 30; kt += 3) {
    tiletop(5); tile(lds_a[0], lds_b[0], lds_a[2], lds_b[2], true);
    tiletop(5); tile(lds_a[1], lds_b[1], lds_a[0], lds_b[0], true);
    tiletop(5); tile(lds_a[2], lds_b[2], lds_a[1], lds_b[1], true);
  }
  tiletop(5); tile(lds_a[0], lds_b[0], nullptr, nullptr, false);  // tile 30
  tiletop(0); tile(lds_a[1], lds_b[1], nullptr, nullptr, false);  // tile 31

#pragma unroll
  for (int z = 0; z < 3; ++z) {
#pragma unroll
    for (int mf = 0; mf < 4; ++mf) {
#pragma unroll
      for (int nf = 0; nf < 4; ++nf) {
        if (z == 2) {
          short4v pk;
#pragma unroll
          for (int r = 0; r < 4; ++r) pk[r] = f2bf(acc[z][mf][nf][r]);
          const int t0 = m0 + wm * 64 + mf * 16 + lgrp * 4;
          const int ch = n0 + wn * 64 + nf * 16 + lrow;
          const int bh = ((t0 >> 11) << 4) + (ch >> 6);
          *reinterpret_cast<short4v*>(
              &Vt[(size_t)bh * 131072 + (size_t)(ch & 63) * 2048 + (t0 & 2047)]) = pk;
        } else {
          short* C = (z == 0) ? Qb : Kb;
#pragma unroll
          for (int r = 0; r < 4; ++r) {
            const int grow = m0 + wm * 64 + mf * 16 + lgrp * 4 + r;
            const int gcol = n0 + wn * 64 + nf * 16 + lrow;
            C[(size_t)grow * 1024 + gcol] = f2bf(acc[z][mf][nf][r]);
          }
        }
      }
    }
  }
}

// ---- single-output GEMM (O-projection), r14 structure (unchanged, passing) ----
template <int MODE>
__device__ __forceinline__ void gemm256_body(const short* __restrict__ A,
                                             const short* __restrict__ B,
                                             void* __restrict__ Cout,
                                             int m0, int n0,
                                             short* __restrict__ la0,
                                             short* __restrict__ la1,
                                             short* __restrict__ la2,
                                             short* __restrict__ lb0,
                                             short* __restrict__ lb1,
                                             short* __restrict__ lb2) {
  const int tid = threadIdx.x;
  const int lane = tid & 63;
  const int w = tid >> 6;
  const int wm = w >> 1, wn = w & 1;
  const int lrow = lane & 15, lgrp = lane >> 4;

  floatx4 acc[4][4] = {};

  const int srow = tid >> 2;
  const int scb = (tid & 3) ^ (srow & 3) ^ ((srow & 4) >> 1);
  const short* ag = A + (size_t)(m0 + srow) * 1024 + scb * 8;
  const short* bg = B + (size_t)(n0 + srow) * 1024 + scb * 8;

  auto stage3 = [&](short* la, short* lb) {
    gload_lds16(ag, la + tid * 8);
    gload_lds16(ag + 128 * 1024, la + (512 + tid) * 8);
    gload_lds16(bg, lb + tid * 8);
    ag += 32; bg += 32;
  };

  const int slA = (lgrp ^ (lrow & 3) ^ ((lrow & 4) >> 1)) * 8;

  auto tile = [&](const short* la, const short* lb, short* na, short* nb, bool pf) {
    if (pf) stage3(na, nb);
    short8 af[4], bf[4];
#pragma unroll
    for (int mf = 0; mf < 4; ++mf) {
      const int row = wm * 64 + mf * 16 + lrow;
      af[mf] = *reinterpret_cast<const short8*>(&la[row * 32 + slA]);
    }
#pragma unroll
    for (int nf = 0; nf < 4; ++nf) {
      const int row = wn * 64 + nf * 16 + lrow;
      bf[nf] = *reinterpret_cast<const short8*>(&lb[row * 32 + slA]);
    }
    __builtin_amdgcn_s_setprio(1);
#pragma unroll
    for (int mf = 0; mf < 4; ++mf)
#pragma unroll
      for (int nf = 0; nf < 4; ++nf)
        acc[mf][nf] = __builtin_amdgcn_mfma_f32_16x16x32_bf16(af[mf], bf[nf], acc[mf][nf], 0, 0, 0);
    __builtin_amdgcn_s_setprio(0);
  };

  auto tiletop = [&](int n) {
    __builtin_amdgcn_sched_barrier(0);
    if (n == 0)
      asm volatile("s_waitcnt vmcnt(0)" ::: "memory");
    else
      asm volatile("s_waitcnt vmcnt(3)" ::: "memory");
    __builtin_amdgcn_s_barrier();
    __builtin_amdgcn_sched_barrier(0);
  };

  stage3(la0, lb0);
  stage3(la1, lb1);

#pragma unroll 1
  for (int kt = 0; kt < 30; kt += 3) {
    tiletop(3); tile(la0, lb0, la2, lb2, true);
    tiletop(3); tile(la1, lb1, la0, lb0, true);
    tiletop(3); tile(la2, lb2, la1, lb1, true);
  }
  tiletop(3); tile(la0, lb0, nullptr, nullptr, false);
  tiletop(0); tile(la1, lb1, nullptr, nullptr, false);

#pragma unroll
  for (int mf = 0; mf < 4; ++mf) {
#pragma unroll
    for (int nf = 0; nf < 4; ++nf) {
#pragma unroll
      for (int r = 0; r < 4; ++r) {
        const int grow = m0 + wm * 64 + mf * 16 + lgrp * 4 + r;
        const int gcol = n0 + wn * 64 + nf * 16 + lrow;
        if (MODE == 1)
          reinterpret_cast<short*>(Cout)[(size_t)grow * 1024 + gcol] = f2bf(acc[mf][nf][r]);
        else
          reinterpret_cast<float*>(Cout)[(size_t)grow * 1024 + gcol] = acc[mf][nf][r];
      }
    }
  }
}

__global__ __launch_bounds__(512) void gemm_out(const short* __restrict__ Ob,
                                                const short* __restrict__ wo,
                                                float* __restrict__ out) {
  __shared__ short lds_a[3][256 * 32];
  __shared__ short lds_b[3][128 * 32];
  const int flat = blockIdx.x;
  const int xcd = flat & 7, rest = flat >> 3;
  const int nblk = rest & 7, pg = rest >> 3;
  const int panel = pg * 8 + xcd;
  gemm256_body<0>(Ob, wo, out, panel * 256, nblk * 128,
                  lds_a[0], lds_a[1], lds_a[2], lds_b[0], lds_b[1], lds_b[2]);
}

// ---------------- flash attention (round 19 body — passing) ----------------
__global__ __launch_bounds__(256, 4) void attn_fwd(const short* __restrict__ Q,
                                                   const short* __restrict__ K,
                                                   const short* __restrict__ Vt,
                                                   short* __restrict__ O) {
  __shared__ short lds_k[2][64 * 64];    // 16 KB
  __shared__ short lds_v[2][64 * 64];    // 16 KB : [d][k] swizzled
  __shared__ short lds_p[4][16 * 64];    //  8 KB : [wave][16q][64k] swizzled (reused per qt)

  const int tid = threadIdx.x;
  const int lane = tid & 63;
  const int w = tid >> 6;                // 0..3
  const int lrow = lane & 15, lgrp = lane >> 4;
  const int flat = blockIdx.x;
  const int bh = flat & 63;              // XCD-locality: same bh -> same XCD
  const int p = flat >> 6;               // 0..15
  const int qc = 4 * (((p & 3) + (p >> 2)) & 3) + (p >> 2);  // Latin-square chunk
  const int b = bh >> 4, h = bh & 15;

  const size_t base = (size_t)b * 2048 * 1024 + h * 64;
  const size_t vbase = (size_t)bh * 131072;

  const int srow = tid >> 3;                         // 0..31
  const int scb = (tid & 7) ^ (srow & 7);
  const size_t koff = (size_t)srow * 1024 + scb * 8;
  const size_t voff = (size_t)srow * 2048 + scb * 8;
  short* const kd0 = &lds_k[0][tid * 8];
  short* const kd1 = &lds_k[1][tid * 8];
  short* const vd0 = &lds_v[0][tid * 8];
  short* const vd1 = &lds_v[1][tid * 8];

  auto stageK = [&](short* ldst, const short* gsrc) {
    gload_lds16(gsrc, ldst);
    gload_lds16(gsrc + 32 * 1024, ldst + 2048);
  };
  auto stageV = [&](short* ldst, const short* gsrc) {
    gload_lds16(gsrc, ldst);
    gload_lds16(gsrc + 32 * 2048, ldst + 2048);
  };

  const int qw = qc * 128 + w * 32;          // wave's first q row
  const int lastkb = 2 * qc + (w >> 1);      // wave's diag KV tile
  const int nkb = 2 * qc + 2;                // block KV-tile count

  short8 qf[2][2];
#pragma unroll
  for (int qt = 0; qt < 2; ++qt) {
    const short* qp = Q + base + (size_t)(qw + qt * 16 + lrow) * 1024 + lgrp * 8;
    qf[qt][0] = *reinterpret_cast<const short8*>(qp);
    qf[qt][1] = *reinterpret_cast<const short8*>(qp + 32);
  }

  floatx4 oacc[2][4] = {};
  float lsum0 = 0.f, lsum1 = 0.f;

  const short* kg = K + base + koff;
  const short* vg = Vt + vbase + voff;

  auto body = [&](int kb, const short* __restrict__ ldsk,
                  const short* __restrict__ ldsv) {
    if (kb > lastkb) return;
    floatx4 s[2][4];
    __builtin_amdgcn_s_setprio(1);
#pragma unroll
    for (int nf = 0; nf < 4; ++nf) {
      const short8 kf0 = *reinterpret_cast<const short8*>(
          &ldsk[(nf * 16 + lrow) * 64 + ((lgrp) ^ (lrow & 7)) * 8]);
      const short8 kf1 = *reinterpret_cast<const short8*>(
          &ldsk[(nf * 16 + lrow) * 64 + ((4 + lgrp) ^ (lrow & 7)) * 8]);
#pragma unroll
      for (int qt = 0; qt < 2; ++qt) {
        floatx4 z = {};
        z = __builtin_amdgcn_mfma_f32_16x16x32_bf16(kf0, qf[qt][0], z, 0, 0, 0);
        z = __builtin_amdgcn_mfma_f32_16x16x32_bf16(kf1, qf[qt][1], z, 0, 0, 0);
        s[qt][nf] = z;
      }
    }
    __builtin_amdgcn_s_setprio(0);

    if (kb == lastkb) {
#pragma unroll
      for (int qt = 0; qt < 2; ++qt)
#pragma unroll
        for (int nf = 0; nf < 4; ++nf)
#pragma unroll
          for (int r = 0; r < 4; ++r) {
            const int kg_ = kb * 64 + nf * 16 + lgrp * 4 + r;
            const int qg_ = qw + qt * 16 + lrow;
            if (kg_ > qg_) s[qt][nf][r] = -1e30f;
          }
    }

    short8 pa[2][2];
#pragma unroll
    for (int qt = 0; qt < 2; ++qt) {
      float ls = 0.f;
#pragma unroll
      for (int nf = 0; nf < 4; ++nf) {
        const float p0 = __builtin_amdgcn_exp2f(s[qt][nf][0]);
        const float p1 = __builtin_amdgcn_exp2f(s[qt][nf][1]);
        const float p2 = __builtin_amdgcn_exp2f(s[qt][nf][2]);
        const float p3 = __builtin_amdgcn_exp2f(s[qt][nf][3]);
        ls += (p0 + p1) + (p2 + p3);
        short4v pk;
        pk.x = f2bf(p0); pk.y = f2bf(p1); pk.z = f2bf(p2); pk.w = f2bf(p3);
        const int c8 = (nf * 4 + lgrp) ^ ((lrow & 7) << 1);
        *reinterpret_cast<short4v*>(&lds_p[w][lrow * 64 + c8 * 4]) = pk;
      }
      if (qt == 0) lsum0 += ls; else lsum1 += ls;
      const int c0 = ((lgrp) ^ (lrow & 7)) * 8;
      const int c1 = ((4 + lgrp) ^ (lrow & 7)) * 8;
      pa[qt][0] = *reinterpret_cast<const short8*>(&lds_p[w][lrow * 64 + c0]);
      pa[qt][1] = *reinterpret_cast<const short8*>(&lds_p[w][lrow * 64 + c1]);
    }

    __builtin_amdgcn_s_setprio(1);
#pragma unroll
    for (int nf = 0; nf < 4; ++nf) {
      const short8 vf0 = *reinterpret_cast<const short8*>(
          &ldsv[(nf * 16 + lrow) * 64 + ((lgrp) ^ (lrow & 7)) * 8]);
      const short8 vf1 = *reinterpret_cast<const short8*>(
          &ldsv[(nf * 16 + lrow) * 64 + ((4 + lgrp) ^ (lrow & 7)) * 8]);
#pragma unroll
      for (int qt = 0; qt < 2; ++qt) {
        oacc[qt][nf] = __builtin_amdgcn_mfma_f32_16x16x32_bf16(pa[qt][0], vf0, oacc[qt][nf], 0, 0, 0);
        oacc[qt][nf] = __builtin_amdgcn_mfma_f32_16x16x32_bf16(pa[qt][1], vf1, oacc[qt][nf], 0, 0, 0);
      }
    }
    __builtin_amdgcn_s_setprio(0);
  };

  stageK(kd0, kg); kg += 65536;
  stageV(vd0, vg); vg += 64;
  __syncthreads();

#pragma unroll 1
  for (int kb = 0; kb < nkb; kb += 2) {
    if (kb + 1 < nkb) { stageK(kd1, kg); kg += 65536; stageV(vd1, vg); vg += 64; }
    body(kb, lds_k[0], lds_v[0]);
    __syncthreads();
    if (kb + 1 >= nkb) break;
    if (kb + 2 < nkb) { stageK(kd0, kg); kg += 65536; stageV(vd0, vg); vg += 64; }
    body(kb + 1, lds_k[1], lds_v[1]);
    __syncthreads();
  }

  lsum0 += __shfl_xor(lsum0, 16, 64);
  lsum0 += __shfl_xor(lsum0, 32, 64);
  lsum1 += __shfl_xor(lsum1, 16, 64);
  lsum1 += __shfl_xor(lsum1, 32, 64);
#pragma unroll
  for (int qt = 0; qt < 2; ++qt) {
    const float lw = qt == 0 ? lsum0 : lsum1;
#pragma unroll
    for (int r = 0; r < 4; ++r) {
      const float linv = 1.0f / __shfl(lw, lgrp * 4 + r, 64);
      const int t = qw + qt * 16 + lgrp * 4 + r;
#pragma unroll
      for (int nf = 0; nf < 4; ++nf)
        O[base + (size_t)t * 1024 + nf * 16 + lrow] = f2bf(oacc[qt][nf][r] * linv);
    }
  }
}

// ---------------- launcher ----------------
extern "C" void kernel_launch(void* const* d_in, const int* in_sizes, int n_in,
                              void* d_out, int out_size, void* d_ws, size_t ws_size,
                              hipStream_t stream) {
  const float* x  = (const float*)d_in[0];
  const float* Wq = (const float*)d_in[1];
  const float* Wk = (const float*)d_in[2];
  const float* Wv = (const float*)d_in[3];
  const float* Wo = (const float*)d_in[4];

  uint8_t* ws = (uint8_t*)d_ws;
  short* xb  = (short*)(ws + 0);           // 8192x1024 bf16  (16 MiB)
  short* wqb = (short*)(ws + 16777216);    // 4 x 1024x1024 bf16, contiguous
  short* wob = (short*)(ws + 23068672);
  short* Qb  = (short*)(ws + 25165824);    // 8192x1024 bf16
  short* Kb  = (short*)(ws + 41943040);
  short* Vt  = (short*)(ws + 58720256);    // [64 bh][64 d][2048 t] bf16
  short* Ob  = (short*)(ws + 75497472);
  if (ws_size < 92274688ull) return;  // fail loudly (output stays poisoned)

  const float qscale = 0.125f * LOG2E;     // fold head-scale + log2e into W_Q

  cvt_all<<<12288, 256, 0, stream>>>(x, Wq, Wk, Wv, Wo, xb, wqb, qscale);

  gemm_qkv<<<256, 512, 0, stream>>>(xb, wqb, Qb, Kb, Vt);
  attn_fwd<<<1024, 256, 0, stream>>>(Qb, Kb, Vt, Ob);
  gemm_out<<<256, 512, 0, stream>>>(Ob, wob, (float*)d_out);
}